// Round 10
// baseline (241.074 us; speedup 1.0000x reference)
//
#include <hip/hip_runtime.h>
#include <stdint.h>

#define BH 2
#define SEQ 2048
#define EMB 1024
#define NH 16
#define HD 64
#define MROWS (BH * SEQ)   // 4096
#define BHN (BH * NH)      // 32
#define LOG2E 1.44269504f

typedef __attribute__((ext_vector_type(8))) short bf16x8;
typedef __attribute__((ext_vector_type(4))) float f32x4;
typedef __attribute__((ext_vector_type(16))) float f32x16;

static __device__ __forceinline__ unsigned short f2bf(float x) {
  union { float f; unsigned int u; } a; a.f = x;
  unsigned int r = a.u + 0x7fffu + ((a.u >> 16) & 1u);
  return (unsigned short)(r >> 16);
}

static __device__ __forceinline__ unsigned int cvtpk(float lo, float hi) {
  unsigned int r;
  asm("v_cvt_pk_bf16_f32 %0, %1, %2" : "=v"(r) : "v"(lo), "v"(hi));
  return r;
}

static __device__ __forceinline__ float vexp2(float x) {
  float r;
  asm("v_exp_f32 %0, %1" : "=v"(r) : "v"(x));
  return r;
}

static __device__ __forceinline__ void plswap(unsigned int& a, unsigned int& b) {
  asm volatile("v_permlane32_swap_b32 %0, %1" : "+v"(a), "+v"(b));
}

// ---------------- fused fp32 -> bf16 conversion (all 7 arrays, 1 launch) ----
struct Conv7 { const float* s[7]; unsigned short* d[7]; };

__global__ __launch_bounds__(256) void conv_all(Conv7 a) {
  const int b = blockIdx.x;
  int r, off;
  if (b < 12288) { r = b >> 12; off = b & 4095; }
  else { int t = b - 12288; r = 3 + (t >> 10); off = t & 1023; }
  const int i = (off * 256 + threadIdx.x) * 4;
  float4 v = *(const float4*)(a.s[r] + i);
  ushort4 o;
  o.x = f2bf(v.x); o.y = f2bf(v.y); o.z = f2bf(v.z); o.w = f2bf(v.w);
  *(ushort4*)(a.d[r] + i) = o;
}

// ---------------- 128x64-tile bf16 GEMM, BK=64, swizzled LDS ---------------
// C = A * Bt^T + bias. Tile covers exactly one head (64 cols). MODE 0:
// z=0 -> bf16 [B,H,S,D] scaled log2e (Q); z=1 -> K; z=2 -> V^T [B,H,D,S].
// MODE 1: fp32 [M x 1024].
struct B3 { const float* p[3]; };
struct Out3 { void* p[3]; };

template <int MODE>
__global__ __launch_bounds__(256) void gemm128(const unsigned short* __restrict__ Abase,
                                               const unsigned short* __restrict__ Bbase,
                                               B3 biases, Out3 outs) {
  __shared__ unsigned short lsm[128 * 64 + 64 * 64];  // 24KB staging; epilogue reuse
  unsigned short* lA = lsm;
  unsigned short* lB = lsm + 128 * 64;
  const int z = blockIdx.z;
  const unsigned short* A  = Abase + (size_t)z * MROWS * EMB;
  const unsigned short* Bt = Bbase + (size_t)z * EMB * EMB;
  const float* bias = biases.p[z];
  const int tid = threadIdx.x;
  const int lane = tid & 63;
  const int w = tid >> 6;
  const int row0 = blockIdx.x * 128;
  const int col0 = blockIdx.y * 64;
  const int wr = (w >> 1) * 64;     // wave m-offset
  const int wc = (w & 1) * 32;      // wave n-offset
  const int r16 = lane & 15;
  const int g = lane >> 4;          // 0..3

  const int s_rowoff = (lane >> 3);                    // 0..7
  const int s_col = ((lane & 7) ^ s_rowoff) * 8;       // pre-swizzled source col

  f32x4 acc[4][2] = {};

  for (int kt = 0; kt < EMB / 64; ++kt) {
    const int k0 = kt * 64;
    __syncthreads();
#pragma unroll
    for (int j = 0; j < 4; ++j) {
      const int chunk = w * 4 + j;          // A chunks 0..15
      const int row = chunk * 8 + s_rowoff;
      __builtin_amdgcn_global_load_lds(
          (const __attribute__((address_space(1))) void*)(A + (size_t)(row0 + row) * EMB + k0 + s_col),
          (__attribute__((address_space(3))) void*)(lA + chunk * 512), 16, 0, 0);
    }
#pragma unroll
    for (int j = 0; j < 2; ++j) {
      const int chunk = w * 2 + j;          // B chunks 0..7
      const int row = chunk * 8 + s_rowoff;
      __builtin_amdgcn_global_load_lds(
          (const __attribute__((address_space(1))) void*)(Bt + (size_t)(col0 + row) * EMB + k0 + s_col),
          (__attribute__((address_space(3))) void*)(lB + chunk * 512), 16, 0, 0);
    }
    __syncthreads();
#pragma unroll
    for (int kk = 0; kk < 2; ++kk) {
      bf16x8 a[4], b[2];
#pragma unroll
      for (int m = 0; m < 4; ++m) {
        const int row = wr + m * 16 + r16;
        a[m] = *(const bf16x8*)(lA + row * 64 + (((kk << 2) + g) ^ (r16 & 7)) * 8);
      }
#pragma unroll
      for (int n = 0; n < 2; ++n) {
        const int row = wc + n * 16 + r16;
        b[n] = *(const bf16x8*)(lB + row * 64 + (((kk << 2) + g) ^ (r16 & 7)) * 8);
      }
#pragma unroll
      for (int m = 0; m < 4; ++m)
#pragma unroll
        for (int n = 0; n < 2; ++n)
          acc[m][n] = __builtin_amdgcn_mfma_f32_16x16x32_bf16(a[m], b[n], acc[m][n], 0, 0, 0);
    }
  }

  if (MODE == 1) {
#pragma unroll
    for (int m = 0; m < 4; ++m)
#pragma unroll
      for (int n = 0; n < 2; ++n) {
        const int colg = col0 + wc + n * 16 + r16;
        const float bv = bias[colg];
#pragma unroll
        for (int j = 0; j < 4; ++j) {
          const int rowg = row0 + wr + m * 16 + g * 4 + j;
          ((float*)outs.p[0])[(size_t)rowg * EMB + colg] = acc[m][n][j] + bv;
        }
      }
  } else {
    const int b_ = row0 >> 11;
    const int s0 = row0 & 2047;
    const int h_ = col0 >> 6;               // tile = exactly one head
    const float scl = (z == 0) ? LOG2E : 1.0f;
    __syncthreads();
    if (z != 2) {
      // [B,H,S,D]: stash [128 s][72] then coalesced rows
#pragma unroll
      for (int m = 0; m < 4; ++m)
#pragma unroll
        for (int n = 0; n < 2; ++n) {
          const int cl = wc + n * 16 + r16;
          const float bv = bias[col0 + cl];
#pragma unroll
          for (int j = 0; j < 4; ++j)
            lsm[(wr + m * 16 + g * 4 + j) * 72 + cl] = f2bf((acc[m][n][j] + bv) * scl);
        }
      __syncthreads();
      const int rr_ = tid >> 1, sh = tid & 1;
      unsigned short* dst = (unsigned short*)outs.p[z] +
          ((size_t)(b_ * NH + h_) * SEQ + s0 + rr_) * 64 + sh * 32;
      uint4 x0 = *(uint4*)&lsm[rr_ * 72 + sh * 32];
      uint4 x1 = *(uint4*)&lsm[rr_ * 72 + sh * 32 + 8];
      uint4 x2 = *(uint4*)&lsm[rr_ * 72 + sh * 32 + 16];
      uint4 x3 = *(uint4*)&lsm[rr_ * 72 + sh * 32 + 24];
      *(uint4*)dst = x0;
      *(uint4*)(dst + 8) = x1;
      *(uint4*)(dst + 16) = x2;
      *(uint4*)(dst + 24) = x3;
    } else {
      // V^T [B,H,D,S]: stash transposed [64 d][136]
#pragma unroll
      for (int m = 0; m < 4; ++m)
#pragma unroll
        for (int n = 0; n < 2; ++n) {
          const int cl = wc + n * 16 + r16;          // d
          const float bv = bias[col0 + cl];
#pragma unroll
          for (int j = 0; j < 4; ++j)
            lsm[cl * 136 + wr + m * 16 + g * 4 + j] = f2bf(acc[m][n][j] + bv);
        }
      __syncthreads();
      const int d_ = tid >> 2, q4 = tid & 3;
      unsigned short* dst = (unsigned short*)outs.p[2] +
          ((size_t)(b_ * NH + h_) * HD + d_) * SEQ + s0 + q4 * 32;
      uint4 y0 = *(uint4*)&lsm[d_ * 136 + q4 * 32];
      uint4 y1 = *(uint4*)&lsm[d_ * 136 + q4 * 32 + 8];
      uint4 y2 = *(uint4*)&lsm[d_ * 136 + q4 * 32 + 16];
      uint4 y3 = *(uint4*)&lsm[d_ * 136 + q4 * 32 + 24];
      *(uint4*)dst = y0;
      *(uint4*)(dst + 8) = y1;
      *(uint4*)(dst + 16) = y2;
      *(uint4*)(dst + 24) = y3;
    }
  }
}

// ---------------- flash attention fwd: 32x32 MFMA, P in registers -----------
// 128-kv iterations (4 subtiles, paired QK chains), 16 barriers total.
__global__ __launch_bounds__(256) void attn_fwd(const unsigned short* __restrict__ Qh,
                                                const unsigned short* __restrict__ Kh,
                                                const unsigned short* __restrict__ Vt,
                                                unsigned short* __restrict__ ctx) {
  __shared__ unsigned short kbuf[2][128 * 64];   // K [kv 128][d 64]
  __shared__ unsigned short vbuf[2][64 * 128];   // V^T [d 64][kv 128]
  const int tid = threadIdx.x;
  const int lane = tid & 63;
  const int w = tid >> 6;
  const int l31 = lane & 31;
  const int hi = lane >> 5;
  const int wg = blockIdx.x;
  const int xcd = wg & 7;
  const int slot = wg >> 3;
  const int bh = xcd + 8 * (slot >> 4);
  const int qb = slot & 15;
  const size_t base = (size_t)bh * SEQ * HD;
  const unsigned short* Q = Qh + base;
  const unsigned short* K = Kh + base;
  const unsigned short* V = Vt + base;
  const int q0 = qb * 128 + w * 32;

  bf16x8 bq[4];
#pragma unroll
  for (int ks = 0; ks < 4; ++ks)
    bq[ks] = *(const bf16x8*)(Q + (size_t)(q0 + l31) * HD + ks * 16 + hi * 8);

  f32x16 oacc0 = {};
  f32x16 oacc1 = {};
  float lsum = 0.f;

  // staging maps: K: 2 thr/row, 4 slots each; V: 4 thr/row, 4 slots each
  const int krow = tid >> 1, khalf = tid & 1;
  const int vrow = tid >> 2, vq = tid & 3;

  const int NT2 = SEQ / 128;  // 16
  uint4 kr[4], vr[4];
  // prologue: tile0 -> buf0 direct; tile1 -> regs
#pragma unroll
  for (int i = 0; i < 4; ++i) {
    uint4 kx = *(const uint4*)(K + (size_t)krow * HD + khalf * 32 + i * 8);
    *(uint4*)(kbuf[0] + krow * 64 + ((khalf * 4 + i) ^ (krow & 7)) * 8) = kx;
    uint4 vx = *(const uint4*)(V + (size_t)vrow * SEQ + vq * 32 + i * 8);
    *(uint4*)(vbuf[0] + vrow * 128 + ((vq * 4 + i) ^ (vrow & 7)) * 8) = vx;
  }
#pragma unroll
  for (int i = 0; i < 4; ++i) {
    kr[i] = *(const uint4*)(K + (size_t)(128 + krow) * HD + khalf * 32 + i * 8);
    vr[i] = *(const uint4*)(V + (size_t)vrow * SEQ + 128 + vq * 32 + i * 8);
  }
  __syncthreads();

  for (int t = 0; t < NT2; ++t) {
    const unsigned short* lK = kbuf[t & 1];
    const unsigned short* lV = vbuf[t & 1];
#pragma unroll
    for (int pr = 0; pr < 2; ++pr) {
      // two independent QK chains, interleaved
      f32x16 st0 = {}, st1 = {};
      __builtin_amdgcn_s_setprio(1);
#pragma unroll
      for (int ks = 0; ks < 4; ++ks) {
        const int sl = ((ks << 1) + hi) ^ (l31 & 7);
        bf16x8 ak0 = *(const bf16x8*)(lK + ((pr * 2) * 32 + l31) * 64 + sl * 8);
        bf16x8 ak1 = *(const bf16x8*)(lK + ((pr * 2 + 1) * 32 + l31) * 64 + sl * 8);
        st0 = __builtin_amdgcn_mfma_f32_32x32x16_bf16(ak0, bq[ks], st0, 0, 0, 0);
        st1 = __builtin_amdgcn_mfma_f32_32x32x16_bf16(ak1, bq[ks], st1, 0, 0, 0);
      }
      __builtin_amdgcn_s_setprio(0);
#pragma unroll
      for (int half = 0; half < 2; ++half) {
        const int sub = pr * 2 + half;
        const f32x16& st = half ? st1 : st0;
        float p[16];
#pragma unroll
        for (int r = 0; r < 16; ++r) p[r] = vexp2(st[r]);
        // tree row-sum (depth 5, no serial chain)
        float q01 = p[0] + p[1], q23 = p[2] + p[3], q45 = p[4] + p[5], q67 = p[6] + p[7];
        float q89 = p[8] + p[9], qab = p[10] + p[11], qcd = p[12] + p[13], qef = p[14] + p[15];
        lsum += ((q01 + q23) + (q45 + q67)) + ((q89 + qab) + (qcd + qef));
#pragma unroll
        for (int h2 = 0; h2 < 2; ++h2) {
          const int b8 = h2 * 8;
          unsigned int a0 = cvtpk(p[b8 + 0], p[b8 + 1]);
          unsigned int b0 = cvtpk(p[b8 + 4], p[b8 + 5]);
          unsigned int a1 = cvtpk(p[b8 + 2], p[b8 + 3]);
          unsigned int b1 = cvtpk(p[b8 + 6], p[b8 + 7]);
          plswap(a0, b0);
          plswap(a1, b1);
          union { unsigned int u[4]; bf16x8 v; } pa;
          pa.u[0] = a0; pa.u[1] = a1; pa.u[2] = b0; pa.u[3] = b1;
          const int kst = sub * 2 + h2;          // kv slice of 16 within 128
          const int s0_ = ((kst << 1) + hi);
          bf16x8 v0 = *(const bf16x8*)(lV + l31 * 128 + (s0_ ^ (l31 & 7)) * 8);
          bf16x8 v1 = *(const bf16x8*)(lV + (32 + l31) * 128 + (s0_ ^ (l31 & 7)) * 8);
          __builtin_amdgcn_s_setprio(1);
          oacc0 = __builtin_amdgcn_mfma_f32_32x32x16_bf16(pa.v, v0, oacc0, 0, 0, 0);
          oacc1 = __builtin_amdgcn_mfma_f32_32x32x16_bf16(pa.v, v1, oacc1, 0, 0, 0);
          __builtin_amdgcn_s_setprio(0);
        }
      }
    }
    // stage t+1 (regs -> other buf), prefetch t+2
    if (t + 1 < NT2) {
      unsigned short* nK = kbuf[(t + 1) & 1];
      unsigned short* nV = vbuf[(t + 1) & 1];
#pragma unroll
      for (int i = 0; i < 4; ++i) {
        *(uint4*)(nK + krow * 64 + ((khalf * 4 + i) ^ (krow & 7)) * 8) = kr[i];
        *(uint4*)(nV + vrow * 128 + ((vq * 4 + i) ^ (vrow & 7)) * 8) = vr[i];
      }
      if (t + 2 < NT2) {
        const int kv2 = (t + 2) * 128;
#pragma unroll
        for (int i = 0; i < 4; ++i) {
          kr[i] = *(const uint4*)(K + (size_t)(kv2 + krow) * HD + khalf * 32 + i * 8);
          vr[i] = *(const uint4*)(V + (size_t)vrow * SEQ + kv2 + vq * 32 + i * 8);
        }
      }
    }
    __syncthreads();
  }

  lsum += __shfl_xor(lsum, 32, 64);
  const float linv = 1.0f / lsum;
  const int b_ = bh >> 4, h_ = bh & 15;
#pragma unroll
  for (int reg = 0; reg < 16; ++reg) {
    const int crow = (reg & 3) + 8 * (reg >> 2) + 4 * hi;
    const float rv = __shfl(linv, crow, 64);
    const size_t rowaddr = ((size_t)(b_ * SEQ + q0 + crow) << 10) + h_ * 64 + l31;
    ctx[rowaddr]      = f2bf(oacc0[reg] * rv);
    ctx[rowaddr + 32] = f2bf(oacc1[reg] * rv);
  }
}

// ---------------- launch ----------------
extern "C" void kernel_launch(void* const* d_in, const int* in_sizes, int n_in,
                              void* d_out, int out_size, void* d_ws, size_t ws_size,
                              hipStream_t stream) {
  const float* q  = (const float*)d_in[0];
  const float* k  = (const float*)d_in[1];
  const float* v  = (const float*)d_in[2];
  const float* Wq = (const float*)d_in[3];
  const float* bq = (const float*)d_in[4];
  const float* Wk = (const float*)d_in[5];
  const float* bk = (const float*)d_in[6];
  const float* Wv = (const float*)d_in[7];
  const float* bv = (const float*)d_in[8];
  const float* Wo = (const float*)d_in[9];
  const float* bo = (const float*)d_in[10];

  char* ws = (char*)d_ws;
  const size_t SZ_ACT = (size_t)MROWS * EMB * 2;  // 8 MiB
  const size_t SZ_W   = (size_t)EMB * EMB * 2;    // 2 MiB
  unsigned short* qb  = (unsigned short*)(ws);
  unsigned short* kb  = (unsigned short*)(ws + SZ_ACT);
  unsigned short* vb  = (unsigned short*)(ws + 2 * SZ_ACT);
  unsigned short* Wqb = (unsigned short*)(ws + 3 * SZ_ACT);
  unsigned short* Wob = (unsigned short*)(ws + 3 * SZ_ACT + 3 * SZ_W);
  unsigned short* Qh  = (unsigned short*)(ws + 3 * SZ_ACT + 4 * SZ_W);
  unsigned short* Kh  = (unsigned short*)(ws + 4 * SZ_ACT + 4 * SZ_W);
  unsigned short* Vt  = (unsigned short*)(ws + 5 * SZ_ACT + 4 * SZ_W);
  unsigned short* ctx = (unsigned short*)(ws + 6 * SZ_ACT + 4 * SZ_W);

  Conv7 ca;
  ca.s[0] = q;  ca.s[1] = k;  ca.s[2] = v;
  ca.s[3] = Wq; ca.s[4] = Wk; ca.s[5] = Wv; ca.s[6] = Wo;
  ca.d[0] = qb; ca.d[1] = kb; ca.d[2] = vb;
  ca.d[3] = Wqb; ca.d[4] = Wqb + EMB * EMB; ca.d[5] = Wqb + 2 * EMB * EMB; ca.d[6] = Wob;
  conv_all<<<16384, 256, 0, stream>>>(ca);

  B3 bqkv; bqkv.p[0] = bq; bqkv.p[1] = bk; bqkv.p[2] = bv;
  Out3 oqkv; oqkv.p[0] = (void*)Qh; oqkv.p[1] = (void*)Kh; oqkv.p[2] = (void*)Vt;
  gemm128<0><<<dim3(MROWS / 128, EMB / 64, 3), 256, 0, stream>>>(qb, Wqb, bqkv, oqkv);

  attn_fwd<<<512, 256, 0, stream>>>(Qh, Kh, Vt, ctx);

  B3 bout; bout.p[0] = bo; bout.p[1] = bo; bout.p[2] = bo;
  Out3 oout; oout.p[0] = d_out; oout.p[1] = d_out; oout.p[2] = d_out;
  gemm128<1><<<dim3(MROWS / 128, EMB / 64, 1), 256, 0, stream>>>(ctx, Wob, bout, oout);
}